// Round 12
// baseline (301.058 us; speedup 1.0000x reference)
//
#include <hip/hip_runtime.h>

#define NROWS 32768
#define NE    1024
#define ED    64
#define CHUNK 64               // codes per LDS chunk (16 KB as [k4][code] f4)
#define NCH   (NE / CHUNK)     // 16 chunks
#define RPW   4                // rows per wave
#define NW    4                // waves per block
#define RPB   (RPW * NW)       // 16 rows per block

typedef float4 f4;

// ---------------------------------------------------------------------------
// Prep: per-code ||e||^2 with numpy pairwise-8 op order (exact f32 replication)
// ---------------------------------------------------------------------------
__global__ void vq_prep(const float* __restrict__ cb, float* __restrict__ ssq)
{
    int j = blockIdx.x * blockDim.x + threadIdx.x;   // 0..1023
    const f4* crow = (const f4*)(cb + (size_t)j * ED);
    f4 v[16];
#pragma unroll
    for (int i = 0; i < 16; ++i) v[i] = crow[i];
    {
#pragma clang fp contract(off)
        float r0 = v[0].x*v[0].x, r1 = v[0].y*v[0].y;
        float r2 = v[0].z*v[0].z, r3 = v[0].w*v[0].w;
        float r4 = v[1].x*v[1].x, r5 = v[1].y*v[1].y;
        float r6 = v[1].z*v[1].z, r7 = v[1].w*v[1].w;
#pragma unroll
        for (int q = 2; q < 16; q += 2) {
            r0 += v[q].x*v[q].x;     r1 += v[q].y*v[q].y;
            r2 += v[q].z*v[q].z;     r3 += v[q].w*v[q].w;
            r4 += v[q+1].x*v[q+1].x; r5 += v[q+1].y*v[q+1].y;
            r6 += v[q+1].z*v[q+1].z; r7 += v[q+1].w*v[q+1].w;
        }
        ssq[j] = ((r0+r1)+(r2+r3)) + ((r4+r5)+(r6+r7));
    }
}

// ---------------------------------------------------------------------------
// Main (r10 structure, two fixes):
//  1. __launch_bounds__(256,4): VGPR cap 128 -> allocator has room to
//     prefetch; grid (2048 blocks x 4 waves = 8192 waves) supplies 8/SIMD.
//  2. z via VMEM broadcast loads (divergent-typed base, all lanes same
//     address, L1-hot) -> vmcnt; e via ds_read_b128 -> lgkmcnt carries DS
//     ONLY. Independent counters, both prefetchable: no per-k4 drain.
// Numerics identical per row to passing r10: cn/ssq numpy pairwise-8;
// dot ascending-k single-acc fmaf; d = fl(fl(cn+ssq)-2*acc); first-index
// argmin (strict < over ascending chunk per lane, lex (d,idx) butterfly).
// ---------------------------------------------------------------------------
__global__ __launch_bounds__(256, 4)
void vq_main(const float* __restrict__ z, const float* __restrict__ cb,
             const float* __restrict__ ssq, float* __restrict__ out,
             float* __restrict__ partials)
{
    __shared__ __align__(16) f4 eL4[16 * CHUNK];     // 16 KB: [k4][code]
    __shared__ int   idxsh[RPB];
    __shared__ float redsh[NW];

    const int tid  = threadIdx.x;
    const int lane = tid & 63;
    const int w    = tid >> 6;                       // wave 0..3 (divergent-typed)
    const int rowbase = blockIdx.x * RPB;

    // z base for this wave's 4 rows — NOT readfirstlane'd: stays VMEM so the
    // inner-loop z reads are global_load_dwordx4 broadcasts (vmcnt), keeping
    // lgkmcnt exclusively for the LDS e-reads.
    const float* zw = z + (size_t)(rowbase + w * RPW) * ED;

    // ---- row norms for this wave's 4 rows, numpy pairwise-8 ----
    float cn[RPW];
    {
        const int rl = (lane >> 3) & 3;      // row within wave's 4 (dup hi lanes)
        const int jj = lane & 7;             // accumulator index
        const float* zr = zw + (size_t)rl * ED;
        float a;
        {
#pragma clang fp contract(off)
            a = 0.f;
#pragma unroll
            for (int i = 0; i < 8; ++i) { float v = zr[8*i + jj]; a += v*v; }
        }
        a += __shfl_xor(a, 1);
        a += __shfl_xor(a, 2);
        a += __shfl_xor(a, 4);
#pragma unroll
        for (int r = 0; r < RPW; ++r) cn[r] = __shfl(a, r * 8);
    }

    float bestv[RPW];
    int   besti[RPW];
#pragma unroll
    for (int r = 0; r < RPW; ++r) { bestv[r] = INFINITY; besti[r] = 0; }

    for (int ch = 0; ch < NCH; ++ch) {
        __syncthreads();   // previous chunk's readers done
        // ---- stage chunk: thread (c = tid&63, h = tid>>6) stages 16 dims ----
        {
            const int c = tid & 63;
            const int h = tid >> 6;
            const f4* crow = (const f4*)(cb + (size_t)(ch * CHUNK + c) * ED
                                         + h * 16);
#pragma unroll
            for (int i = 0; i < 4; ++i)
                eL4[(4*h + i) * CHUNK + c] = crow[i];   // conflict-free b128
        }
        __syncthreads();

        const float sq = ssq[ch * CHUNK + lane];     // coalesced, L2-hot

        float a0 = 0.f, a1 = 0.f, a2 = 0.f, a3 = 0.f;

#pragma unroll 4
        for (int k4 = 0; k4 < 16; ++k4) {
            f4 e  = eL4[k4 * CHUNK + lane];          // ds_read_b128 (lgkmcnt)
            f4 z0 = *(const f4*)(zw + 0*ED + 4*k4);  // global b128 broadcast
            f4 z1 = *(const f4*)(zw + 1*ED + 4*k4);  //   (vmcnt, L1-hot)
            f4 z2 = *(const f4*)(zw + 2*ED + 4*k4);
            f4 z3 = *(const f4*)(zw + 3*ED + 4*k4);
            a0 = fmaf(e.x, z0.x, a0); a0 = fmaf(e.y, z0.y, a0);
            a0 = fmaf(e.z, z0.z, a0); a0 = fmaf(e.w, z0.w, a0);
            a1 = fmaf(e.x, z1.x, a1); a1 = fmaf(e.y, z1.y, a1);
            a1 = fmaf(e.z, z1.z, a1); a1 = fmaf(e.w, z1.w, a1);
            a2 = fmaf(e.x, z2.x, a2); a2 = fmaf(e.y, z2.y, a2);
            a2 = fmaf(e.z, z2.z, a2); a2 = fmaf(e.w, z2.w, a2);
            a3 = fmaf(e.x, z3.x, a3); a3 = fmaf(e.y, z3.y, a3);
            a3 = fmaf(e.z, z3.z, a3); a3 = fmaf(e.w, z3.w, a3);
        }

        {
#pragma clang fp contract(off)
            const int j = ch * CHUNK + lane;
            float d0 = (cn[0] + sq) - 2.0f * a0;     // 2*acc exact
            float d1 = (cn[1] + sq) - 2.0f * a1;
            float d2 = (cn[2] + sq) - 2.0f * a2;
            float d3 = (cn[3] + sq) - 2.0f * a3;
            if (d0 < bestv[0]) { bestv[0] = d0; besti[0] = j; }
            if (d1 < bestv[1]) { bestv[1] = d1; besti[1] = j; }
            if (d2 < bestv[2]) { bestv[2] = d2; besti[2] = j; }
            if (d3 < bestv[3]) { bestv[3] = d3; besti[3] = j; }
        }
    }

    // ---- cross-lane lexicographic (val, idx) argmin per row ----
#pragma unroll
    for (int r = 0; r < RPW; ++r) {
        float v = bestv[r];
        int   i = besti[r];
#pragma unroll
        for (int m = 1; m < 64; m <<= 1) {
            float ov = __shfl_xor(v, m);
            int   oi = __shfl_xor(i, m);
            if (ov < v || (ov == v && oi < i)) { v = ov; i = oi; }
        }
        if (lane == 0) idxsh[w * RPW + r] = i & (NE - 1);
    }
    __syncthreads();

    // ---- uniform coalesced idx store (f32) ----
    if (tid < RPB)
        out[(size_t)NROWS * ED + rowbase + tid] = (float)idxsh[tid];

    // ---- epilogue: thread -> (row = tid>>4, f4-col = tid&15) ----
    const int erow = tid >> 4;
    const int q4   = tid & 15;
    const int gi   = idxsh[erow];
    f4 e  = *(const f4*)(cb + (size_t)gi * ED + q4 * 4);
    f4 zz = *(const f4*)(z + (size_t)(rowbase + erow) * ED + q4 * 4);
    float lp;
    f4 o;
    {
#pragma clang fp contract(off)
        float d0 = e.x - zz.x; o.x = zz.x + d0;
        float d1 = e.y - zz.y; o.y = zz.y + d1;
        float d2 = e.z - zz.z; o.z = zz.z + d2;
        float d3 = e.w - zz.w; o.w = zz.w + d3;
        lp = ((d0*d0 + d1*d1) + (d2*d2 + d3*d3));
    }
    *(f4*)(out + (size_t)(rowbase + erow) * ED + q4 * 4) = o;

    // ---- deterministic loss partial ----
#pragma unroll
    for (int m = 1; m < 64; m <<= 1) lp += __shfl_xor(lp, m);
    if (lane == 0) redsh[w] = lp;
    __syncthreads();
    if (tid == 0)
        partials[blockIdx.x] = (redsh[0] + redsh[1]) + (redsh[2] + redsh[3]);
}

// ---------------------------------------------------------------------------
// Finalize: deterministic tree-sum of 2048 partials -> loss scalar (f32)
// ---------------------------------------------------------------------------
__global__ void vq_finalize(const float* __restrict__ partials,
                            float* __restrict__ out)
{
    __shared__ float red[256];
    int t = threadIdx.x;
    float a = (partials[t]        + partials[t + 256])
            + (partials[t + 512]  + partials[t + 768]);
    float b = (partials[t + 1024] + partials[t + 1280])
            + (partials[t + 1536] + partials[t + 1792]);
    red[t] = a + b;
    __syncthreads();
    for (int m = 128; m > 0; m >>= 1) {
        if (t < m) red[t] += red[t + m];
        __syncthreads();
    }
    if (t == 0) {
        float mean = red[0] / (float)((size_t)NROWS * ED);
        out[(size_t)NROWS * ED + NROWS] = mean + 0.25f * mean;  // (1+BETA)*mean
    }
}

extern "C" void kernel_launch(void* const* d_in, const int* in_sizes, int n_in,
                              void* d_out, int out_size, void* d_ws, size_t ws_size,
                              hipStream_t stream)
{
    (void)in_sizes; (void)n_in; (void)out_size; (void)ws_size;
    const float* z  = (const float*)d_in[0];
    const float* cb = (const float*)d_in[1];
    float* out = (float*)d_out;
    float* ssq      = (float*)d_ws;          // 1024 f32
    float* partials = ssq + NE;              // 2048 f32

    vq_prep<<<4, 256, 0, stream>>>(cb, ssq);
    vq_main<<<2048, 256, 0, stream>>>(z, cb, ssq, out, partials);
    vq_finalize<<<1, 256, 0, stream>>>(partials, out);
}

// Round 13
// 84.703 us; speedup vs baseline: 3.5543x; 3.5543x over previous
//
#include <hip/hip_runtime.h>

#define NROWS 32768
#define NE    1024
#define ED    64
#define CHUNK 128              // codes per LDS chunk (32 KB transposed)
#define NCH   (NE / CHUNK)     // 8 chunks
#define RPW   4                // rows per wave
#define NW    8                // waves per block (512 threads)
#define RPB   (RPW * NW)       // 32 rows per block

typedef float4 f4;
typedef float2 f2;

// ---------------------------------------------------------------------------
// Prep: per-code ||e||^2 with numpy pairwise-8 op order (exact f32 replication)
// ---------------------------------------------------------------------------
__global__ void vq_prep(const float* __restrict__ cb, float* __restrict__ ssq)
{
    int j = blockIdx.x * blockDim.x + threadIdx.x;   // 0..1023
    const f4* crow = (const f4*)(cb + (size_t)j * ED);
    f4 v[16];
#pragma unroll
    for (int i = 0; i < 16; ++i) v[i] = crow[i];
    {
#pragma clang fp contract(off)
        float r0 = v[0].x*v[0].x, r1 = v[0].y*v[0].y;
        float r2 = v[0].z*v[0].z, r3 = v[0].w*v[0].w;
        float r4 = v[1].x*v[1].x, r5 = v[1].y*v[1].y;
        float r6 = v[1].z*v[1].z, r7 = v[1].w*v[1].w;
#pragma unroll
        for (int q = 2; q < 16; q += 2) {
            r0 += v[q].x*v[q].x;     r1 += v[q].y*v[q].y;
            r2 += v[q].z*v[q].z;     r3 += v[q].w*v[q].w;
            r4 += v[q+1].x*v[q+1].x; r5 += v[q+1].y*v[q+1].y;
            r6 += v[q+1].z*v[q+1].z; r7 += v[q+1].w*v[q+1].w;
        }
        ssq[j] = ((r0+r1)+(r2+r3)) + ((r4+r5)+(r6+r7));
    }
}

// ---------------------------------------------------------------------------
// Main = r7's proven structure with doubled wave-parallelism:
//  - 1024 blocks x 512 thr; block = 32 rows; 8 waves x 4 rows (disjoint).
//    8192 waves -> 8/SIMD grid-resident; LDS ~33 KB -> 4 blocks/CU.
//  - codebook chunk (128 codes) transposed in LDS [64 dim][128 code];
//    lane owns code pair {2*lane, 2*lane+1} (f2 reads, 2-way = free).
//  - z fragments (row,k4) wave-uniform -> s_load_dwordx4 (SMEM, r7-proven);
//    no launch_bounds min-waves (r8's clamp-spill lesson).
// Numerics identical per row to passing r3/r6/r7: cn/ssq numpy pairwise-8;
// dot ascending-k single-acc fmaf; d = fl(fl(cn+ssq)-2*acc); first-index
// argmin (strict < ascending chunks per lane, lex (d,idx) butterfly).
// ---------------------------------------------------------------------------
__global__ __launch_bounds__(512)
void vq_main(const float* __restrict__ z, const float* __restrict__ cb,
             const float* __restrict__ ssq, float* __restrict__ out,
             float* __restrict__ partials)
{
    __shared__ __align__(16) float et[ED * CHUNK];   // 32 KB transposed chunk
    __shared__ int   idxsh[RPB];
    __shared__ float wsum[NW];

    const int tid  = threadIdx.x;
    const int lane = tid & 63;
    const int w    = tid >> 6;                               // wave 0..7
    const int w_u  = __builtin_amdgcn_readfirstlane(w);      // scalar wave id
    const int rowbase = blockIdx.x * RPB;

    const float* zw = z + (size_t)(rowbase + w_u * RPW) * ED; // scalar base

    // ---- row norms for this wave's 4 rows, numpy pairwise-8 ----
    float cn[RPW];
    {
        const int rl = (lane >> 3) & 3;      // row within wave's 4 (dup hi half)
        const int jj = lane & 7;             // accumulator index
        const float* zr = zw + (size_t)rl * ED;
        float a;
        {
#pragma clang fp contract(off)
            a = 0.f;
#pragma unroll
            for (int i = 0; i < 8; ++i) { float v = zr[8*i + jj]; a += v*v; }
        }
        a += __shfl_xor(a, 1);
        a += __shfl_xor(a, 2);
        a += __shfl_xor(a, 4);
#pragma unroll
        for (int r = 0; r < RPW; ++r) cn[r] = __shfl(a, r * 8);
    }

    float bestv[RPW];
    int   besti[RPW];
#pragma unroll
    for (int r = 0; r < RPW; ++r) { bestv[r] = INFINITY; besti[r] = 0; }

    const f2* et2 = (const f2*)et;           // [64 dim][64 f2-col]

    for (int ch = 0; ch < NCH; ++ch) {
        __syncthreads();   // previous chunk's readers done
        // ---- stage chunk transposed: 4 threads per code (16 dims each) ----
        {
            const int c = tid & 127;          // code within chunk
            const int h = tid >> 7;           // dim quarter 0..3
            const f4* crow = (const f4*)(cb + (size_t)(ch * CHUNK + c) * ED
                                         + h * 16);
#pragma unroll
            for (int i = 0; i < 4; ++i) {
                f4 t = crow[i];
                const int dim = h * 16 + 4 * i;
                et[(dim+0) * CHUNK + c] = t.x;
                et[(dim+1) * CHUNK + c] = t.y;
                et[(dim+2) * CHUNK + c] = t.z;
                et[(dim+3) * CHUNK + c] = t.w;
            }
        }
        __syncthreads();

        // ssq for lane's code pair: coalesced f2 from global (L2-hot)
        f2 sv = ((const f2*)(ssq + ch * CHUNK))[lane];
        float svq[2] = {sv.x, sv.y};

        float acc[RPW][2];
#pragma unroll
        for (int r = 0; r < RPW; ++r) acc[r][0] = acc[r][1] = 0.f;

#pragma unroll 4
        for (int k4 = 0; k4 < 16; ++k4) {
            // e: lane's code pair at dims 4k4..4k4+3 (LDS pipe, 2-way free)
            f2 e0 = et2[(4*k4+0) * 64 + lane];
            f2 e1 = et2[(4*k4+1) * 64 + lane];
            f2 e2 = et2[(4*k4+2) * 64 + lane];
            f2 e3 = et2[(4*k4+3) * 64 + lane];
            // z: wave-uniform fragments -> s_load_dwordx4 (SMEM pipe)
            f4 z0 = *(const f4*)(zw + 0*ED + 4*k4);
            f4 z1 = *(const f4*)(zw + 1*ED + 4*k4);
            f4 z2 = *(const f4*)(zw + 2*ED + 4*k4);
            f4 z3 = *(const f4*)(zw + 3*ED + 4*k4);
#define ROWFMA(r, zz)                                                    \
            acc[r][0] = fmaf(zz.x, e0.x, acc[r][0]);                     \
            acc[r][1] = fmaf(zz.x, e0.y, acc[r][1]);                     \
            acc[r][0] = fmaf(zz.y, e1.x, acc[r][0]);                     \
            acc[r][1] = fmaf(zz.y, e1.y, acc[r][1]);                     \
            acc[r][0] = fmaf(zz.z, e2.x, acc[r][0]);                     \
            acc[r][1] = fmaf(zz.z, e2.y, acc[r][1]);                     \
            acc[r][0] = fmaf(zz.w, e3.x, acc[r][0]);                     \
            acc[r][1] = fmaf(zz.w, e3.y, acc[r][1]);
            ROWFMA(0, z0) ROWFMA(1, z1) ROWFMA(2, z2) ROWFMA(3, z3)
#undef ROWFMA
        }

        {
#pragma clang fp contract(off)
#pragma unroll
            for (int r = 0; r < RPW; ++r) {
#pragma unroll
                for (int q = 0; q < 2; ++q) {
                    float t1 = cn[r] + svq[q];
                    float d  = t1 - 2.0f * acc[r][q];      // 2*acc exact
                    int j = ch * CHUNK + lane * 2 + q;
                    if (d < bestv[r]) { bestv[r] = d; besti[r] = j; }
                }
            }
        }
    }

    // ---- cross-lane lexicographic (val, idx) argmin + epilogue ----
    float lp = 0.f;
#pragma unroll
    for (int r = 0; r < RPW; ++r) {
        float v = bestv[r];
        int   i = besti[r];
#pragma unroll
        for (int m = 1; m < 64; m <<= 1) {
            float ov = __shfl_xor(v, m);
            int   oi = __shfl_xor(i, m);
            if (ov < v || (ov == v && oi < i)) { v = ov; i = oi; }
        }
        i &= (NE - 1);                       // defensive no-op
        const int grow = rowbase + w * RPW + r;
        float zq, zz, diff, st;
        {
#pragma clang fp contract(off)
            zq   = cb[(size_t)i * ED + lane];
            zz   = z [(size_t)grow * ED + lane];
            diff = zq - zz;                  // (z_q - z)
            st   = zz + diff;                // z + sg(z_q - z)
            lp  += diff * diff;
        }
        out[(size_t)grow * ED + lane] = st;
        if (lane == 0) idxsh[w * RPW + r] = i;
    }

    // ---- deterministic loss partial ----
#pragma unroll
    for (int m = 1; m < 64; m <<= 1) lp += __shfl_xor(lp, m);
    if (lane == 0) wsum[w] = lp;
    __syncthreads();

    // ---- uniform coalesced idx store (f32) ----
    if (tid < RPB) {
        int iv = idxsh[tid] & (NE - 1);
        out[(size_t)NROWS * ED + rowbase + tid] = (float)iv;
    }
    if (tid == 0)
        partials[blockIdx.x] = (((wsum[0]+wsum[1]) + (wsum[2]+wsum[3]))
                              + ((wsum[4]+wsum[5]) + (wsum[6]+wsum[7])));
}

// ---------------------------------------------------------------------------
// Finalize: deterministic tree-sum of 1024 partials -> loss scalar (f32)
// ---------------------------------------------------------------------------
__global__ void vq_finalize(const float* __restrict__ partials,
                            float* __restrict__ out)
{
    __shared__ float red[256];
    int t = threadIdx.x;
    float s = (partials[t] + partials[t + 256]) + (partials[t + 512] + partials[t + 768]);
    red[t] = s;
    __syncthreads();
    for (int m = 128; m > 0; m >>= 1) {
        if (t < m) red[t] += red[t + m];
        __syncthreads();
    }
    if (t == 0) {
        float mean = red[0] / (float)((size_t)NROWS * ED);
        out[(size_t)NROWS * ED + NROWS] = mean + 0.25f * mean;  // (1+BETA)*mean
    }
}

extern "C" void kernel_launch(void* const* d_in, const int* in_sizes, int n_in,
                              void* d_out, int out_size, void* d_ws, size_t ws_size,
                              hipStream_t stream)
{
    (void)in_sizes; (void)n_in; (void)out_size; (void)ws_size;
    const float* z  = (const float*)d_in[0];
    const float* cb = (const float*)d_in[1];
    float* out = (float*)d_out;
    float* ssq      = (float*)d_ws;          // 1024 f32
    float* partials = ssq + NE;              // 1024 f32

    vq_prep<<<4, 256, 0, stream>>>(cb, ssq);
    vq_main<<<1024, 512, 0, stream>>>(z, cb, ssq, out, partials);
    vq_finalize<<<1, 256, 0, stream>>>(partials, out);
}